// Round 9
// baseline (559.677 us; speedup 1.0000x reference)
//
#include <hip/hip_runtime.h>

using ushort = unsigned short;

#define DEVFN static __device__ __forceinline__

constexpr int H = 128;
constexpr int N_AA = 262144, N_CG = 65536;
constexpr int E_CC = 262144, E_CA = 524288;
constexpr int B_GR = 64;

typedef __attribute__((ext_vector_type(8))) short bf16x8;
typedef __attribute__((ext_vector_type(4))) float f32x4;

DEVFN float elu(float x) { return x > 0.f ? x : __expf(x) - 1.f; }

DEVFN float bf2f(ushort s) { return __uint_as_float(((unsigned)s) << 16); }
DEVFN ushort f2bf(float f) {
  unsigned u = __float_as_uint(f);
  return (ushort)((u + 0x7FFFu + ((u >> 16) & 1u)) >> 16);
}
DEVFN ushort4 pack4(const f32x4& a) {
  return make_ushort4(f2bf(a[0]), f2bf(a[1]), f2bf(a[2]), f2bf(a[3]));
}

DEVFN void fma4(float4& c, float a, float4 w) {
  c.x += a * w.x; c.y += a * w.y; c.z += a * w.z; c.w += a * w.w;
}

// ================= graph prep (merged kernels) =================
__global__ void hist4_kernel(const int* __restrict__ src_cc, const int* __restrict__ dst_cc,
                             const int* __restrict__ src_ca, const int* __restrict__ dst_ca,
                             int* __restrict__ c_scc, int* __restrict__ c_dcc,
                             int* __restrict__ c_sca, int* __restrict__ c_dca) {
  int i = blockIdx.x * blockDim.x + threadIdx.x;
  int stride = gridDim.x * blockDim.x;
  const int T = 2 * E_CC + 2 * E_CA;
  for (; i < T; i += stride) {
    const int* a; int* c; int j = i;
    if (j < E_CC) { a = src_cc; c = c_scc; }
    else if (j < 2 * E_CC) { a = dst_cc; c = c_dcc; j -= E_CC; }
    else if (j < 2 * E_CC + E_CA) { a = src_ca; c = c_sca; j -= 2 * E_CC; }
    else { a = dst_ca; c = c_dca; j -= 2 * E_CC + E_CA; }
    atomicAdd(&c[a[j]], 1);
  }
}

// graph_id is SORTED -> per-graph counts via binary-search boundaries (no atomics)
__global__ void graph_count_kernel(const int* __restrict__ gid, int n, int* __restrict__ counts) {
  int b = threadIdx.x;
  auto lb = [&](int v) {
    int lo = 0, hi = n;
    while (lo < hi) { int m = (lo + hi) >> 1; if (gid[m] < v) lo = m + 1; else hi = m; }
    return lo;
  };
  int s = lb(b), e = lb(b + 1);
  counts[b] = e - s;
}

// all 4 degree arrays (counts and outputs laid out contiguously, same order)
__global__ void deg_all_kernel(const int* __restrict__ cnt, float* __restrict__ d) {
  int i = blockIdx.x * blockDim.x + threadIdx.x;
  int c = cnt[i]; if (c < 1) c = 1;
  d[i] = rsqrtf((float)c);
}

// 5x W swizzle + 1x W_aa0 pad in one launch.
// Wsw[r*128+j] = bf16(W[k][r]), k = (j - (r&15)*8) & 127  (matches LDS read swizzle)
__global__ void wprep_kernel(const float* __restrict__ w0, const float* __restrict__ w1,
                             const float* __restrict__ w2, const float* __restrict__ w3,
                             const float* __restrict__ w4,
                             ushort* __restrict__ o0, ushort* __restrict__ o1,
                             ushort* __restrict__ o2, ushort* __restrict__ o3,
                             ushort* __restrict__ o4,
                             const float* __restrict__ wa, ushort* __restrict__ oa) {
  int idx = blockIdx.x * 256 + threadIdx.x;  // grid 336*256
  if (idx < 81920) {
    int which = idx >> 14, id = idx & 16383;
    const float* W = which == 0 ? w0 : which == 1 ? w1 : which == 2 ? w2 : which == 3 ? w3 : w4;
    ushort* O = which == 0 ? o0 : which == 1 ? o1 : which == 2 ? o2 : which == 3 ? o3 : o4;
    int r = id >> 7, j = id & 127;
    int k = (j - ((r & 15) << 3)) & 127;
    O[id] = f2bf(W[k * 128 + r]);
  } else if (idx < 86016) {
    int id = idx - 81920;
    int n = id >> 5, k = id & 31;
    oa[id] = (k < 16) ? f2bf(wa[k * 128 + n]) : (ushort)0;
  }
}

// merged exclusive scans (cc: 64 blocks, ca: 256 blocks; bsum = 320 ints)
__global__ void scan1_kernel(const int* __restrict__ in_cc, int* __restrict__ out_cc,
                             const int* __restrict__ in_ca, int* __restrict__ out_ca,
                             int* __restrict__ bsum) {
  __shared__ int l[256];
  int b = blockIdx.x, tid = threadIdx.x;
  const int* in; int* out; int bi;
  if (b < 64) { in = in_cc; out = out_cc; bi = b; } else { in = in_ca; out = out_ca; bi = b - 64; }
  int base = bi * 1024 + tid * 4;
  int4 v = *(const int4*)&in[base];
  int s = v.x + v.y + v.z + v.w;
  l[tid] = s; __syncthreads();
  for (int off = 1; off < 256; off <<= 1) {
    int t = (tid >= off) ? l[tid - off] : 0;
    __syncthreads();
    if (tid >= off) l[tid] += t;
    __syncthreads();
  }
  int excl = l[tid] - s;
  if (tid == 255) bsum[b] = l[255];
  int4 o; o.x = excl; o.y = o.x + v.x; o.z = o.y + v.y; o.w = o.z + v.z;
  *(int4*)&out[base] = o;
}

__global__ void scan2_kernel(int* __restrict__ bsum) {
  __shared__ int l[256];
  int b = blockIdx.x, tid = threadIdx.x;
  int* bs = bsum + (b ? 64 : 0);
  int nb = b ? 256 : 64;
  int v = (tid < nb) ? bs[tid] : 0;
  l[tid] = v; __syncthreads();
  for (int off = 1; off < 256; off <<= 1) {
    int t = (tid >= off) ? l[tid - off] : 0;
    __syncthreads();
    if (tid >= off) l[tid] += t;
    __syncthreads();
  }
  if (tid < nb) bs[tid] = l[tid] - v;
}

__global__ void scan3_kernel(int* __restrict__ offs_cc, int* __restrict__ cur_cc,
                             int* __restrict__ offs_ca, int* __restrict__ cur_ca,
                             const int* __restrict__ bsum) {
  int i = blockIdx.x * blockDim.x + threadIdx.x;
  if (i < N_CG) {
    int o = offs_cc[i] + bsum[i >> 10];
    offs_cc[i] = o; cur_cc[i] = o;
  } else if (i < N_CG + N_AA) {
    int j = i - N_CG;
    int o = offs_ca[j] + bsum[64 + (j >> 10)];
    offs_ca[j] = o; cur_ca[j] = o;
  }
}

__global__ void place2_kernel(const int* __restrict__ src_cc, const int* __restrict__ dst_cc,
                              const int* __restrict__ src_ca, const int* __restrict__ dst_ca,
                              int* __restrict__ cur_cc, int* __restrict__ sorted_cc,
                              int* __restrict__ cur_ca, int* __restrict__ sorted_ca) {
  int i = blockIdx.x * blockDim.x + threadIdx.x;
  int stride = gridDim.x * blockDim.x;
  for (; i < E_CC + E_CA; i += stride) {
    if (i < E_CC) {
      int d = dst_cc[i];
      int slot = atomicAdd(&cur_cc[d], 1);
      sorted_cc[slot] = src_cc[i];
    } else {
      int j = i - E_CC;
      int d = dst_ca[j];
      int slot = atomicAdd(&cur_ca[d], 1);
      sorted_ca[slot] = src_ca[j];
    }
  }
}

// ================= CSR gather: out[d] = d_in[d] * sum_e d_out[src]*h[src] =================
__global__ __launch_bounds__(256) void gather_kernel(
    const ushort* __restrict__ h, const int* __restrict__ sorted_src,
    const int* __restrict__ offs, const int* __restrict__ cnt,
    const float* __restrict__ dout, const float* __restrict__ din,
    ushort* __restrict__ out, int ndst) {
  int lane = threadIdx.x & 31;
  int g0 = (blockIdx.x * blockDim.x + threadIdx.x) >> 5;
  int gstride = (gridDim.x * blockDim.x) >> 5;
  for (int d = g0; d < ndst; d += gstride) {
    int o = offs[d], c = cnt[d];
    float ax = 0.f, ay = 0.f, az = 0.f, aw = 0.f;
    for (int e = o; e < o + c; ++e) {
      int s = sorted_src[e];
      float w = dout[s];
      ushort4 u = *(const ushort4*)&h[(size_t)s * H + lane * 4];
      ax += w * bf2f(u.x); ay += w * bf2f(u.y);
      az += w * bf2f(u.z); aw += w * bf2f(u.w);
    }
    float di = din[d];
    ushort4 r = make_ushort4(f2bf(ax * di), f2bf(ay * di), f2bf(az * di), f2bf(aw * di));
    *(ushort4*)&out[(size_t)d * H + lane * 4] = r;
  }
}

// ================= MFMA building blocks =================
// Per-wave, 32 nodes = 2 groups of 16; W-fragment LDS reads shared across groups.
// C/D layout (mfma_f32_16x16x32_bf16): lane(t=lane&15,q=lane>>4) owns node t,
// feats nf*16+q*4+{0..3}. B-frag: lane(t,q) holds node t feats [ks*32+q*8,+8).

DEVFN void stage_w(const ushort* __restrict__ g, ushort* l, int tid) {
  for (int i = tid; i < 2048; i += 512)  // 32 KB
    *((uint4*)l + i) = *((const uint4*)g + i);
}

DEVFN void load_bfrag(const ushort* __restrict__ A, size_t mrow, int q, bf16x8 bfr[4]) {
#pragma unroll
  for (int ks = 0; ks < 4; ks++)
    bfr[ks] = *(const bf16x8*)(A + mrow + ks * 32 + q * 8);
}

DEVFN void load_skip_raw(const ushort* __restrict__ skip, size_t mrow, int q, ushort4 sk[8]) {
#pragma unroll
  for (int nf = 0; nf < 8; nf++)
    sk[nf] = *(const ushort4*)&skip[mrow + nf * 16 + q * 4];
}

// swizzled-LDS 128x128 GEMM, 2 node-groups sharing each W read (32 reads, 64 MFMA)
DEVFN void gemm128_lds2(const ushort* __restrict__ Wlds,
                        const bf16x8 b0[4], const bf16x8 b1[4],
                        f32x4 A0[8], f32x4 A1[8], int t, int q) {
#pragma unroll
  for (int ks = 0; ks < 4; ks++) {
    int coff = (ks * 64 + q * 16 + t * 16) & 255;
#pragma unroll
    for (int nf = 0; nf < 8; nf++) {
      bf16x8 wv = *(const bf16x8*)((const char*)Wlds + (nf * 16 + t) * 256 + coff);
      A0[nf] = __builtin_amdgcn_mfma_f32_16x16x32_bf16(wv, b0[ks], A0[nf], 0, 0, 0);
      A1[nf] = __builtin_amdgcn_mfma_f32_16x16x32_bf16(wv, b1[ks], A1[nf], 0, 0, 0);
    }
  }
}

// chained GEMM, 2 groups: C-layout regs -> 2KB/group wave-private LDS (two 64-feat
// halves, t*8-rotated) -> B-frags -> shared-W MFMA accumulate.
DEVFN void chained_gemm2(const ushort* __restrict__ Wlds, char* cb0, char* cb1,
                         int t, int q,
                         const f32x4 i0[8], const f32x4 i1[8],
                         f32x4 A0[8], f32x4 A1[8]) {
  const int tb = t * 8;
  char* row0 = cb0 + t * 128;
  char* row1 = cb1 + t * 128;
#pragma unroll
  for (int half = 0; half < 2; half++) {
    asm volatile("s_waitcnt lgkmcnt(0)" ::: "memory");  // prior half's reads returned
#pragma unroll
    for (int nfl = 0; nfl < 4; nfl++) {
      int off = (nfl * 32 + q * 8 + tb) & 127;
      *(ushort4*)(row0 + off) = pack4(i0[half * 4 + nfl]);
      *(ushort4*)(row1 + off) = pack4(i1[half * 4 + nfl]);
    }
    asm volatile("s_waitcnt lgkmcnt(0)" ::: "memory");  // writes visible
#pragma unroll
    for (int ksl = 0; ksl < 2; ksl++) {
      int ks = half * 2 + ksl;
      int olo = (ksl * 64 + q * 16 + tb) & 127;
      int ohi = (ksl * 64 + q * 16 + 8 + tb) & 127;
      uint2 lo0 = *(const uint2*)(row0 + olo);
      uint2 hi0 = *(const uint2*)(row0 + ohi);
      uint2 lo1 = *(const uint2*)(row1 + olo);
      uint2 hi1 = *(const uint2*)(row1 + ohi);
      union { uint4 u; bf16x8 v; } b0, b1;
      b0.u = make_uint4(lo0.x, lo0.y, hi0.x, hi0.y);
      b1.u = make_uint4(lo1.x, lo1.y, hi1.x, hi1.y);
      int coff = (ks * 64 + q * 16 + t * 16) & 255;
#pragma unroll
      for (int nf = 0; nf < 8; nf++) {
        bf16x8 wv = *(const bf16x8*)((const char*)Wlds + (nf * 16 + t) * 256 + coff);
        A0[nf] = __builtin_amdgcn_mfma_f32_16x16x32_bf16(wv, b0.v, A0[nf], 0, 0, 0);
        A1[nf] = __builtin_amdgcn_mfma_f32_16x16x32_bf16(wv, b1.v, A1[nf], 0, 0, 0);
      }
    }
  }
}

template<bool ACT>
DEVFN void bias_act(f32x4 a[8], const float* __restrict__ bias, int q) {
#pragma unroll
  for (int nf = 0; nf < 8; nf++) {
    float4 bb = *(const float4*)&bias[nf * 16 + q * 4];
    a[nf][0] += bb.x; a[nf][1] += bb.y; a[nf][2] += bb.z; a[nf][3] += bb.w;
    if constexpr (ACT) {
#pragma unroll
      for (int e = 0; e < 4; e++) a[nf][e] = elu(a[nf][e]);
    }
  }
}

DEVFN void add_reg(f32x4 a[8], const f32x4 b[8]) {
#pragma unroll
  for (int nf = 0; nf < 8; nf++)
#pragma unroll
    for (int e = 0; e < 4; e++) a[nf][e] += b[nf][e];
}

DEVFN void add_skip_r(f32x4 a[8], const ushort4 sk[8]) {
#pragma unroll
  for (int nf = 0; nf < 8; nf++) {
    a[nf][0] += bf2f(sk[nf].x); a[nf][1] += bf2f(sk[nf].y);
    a[nf][2] += bf2f(sk[nf].z); a[nf][3] += bf2f(sk[nf].w);
  }
}

DEVFN void layernorm(f32x4 a[8], const float* __restrict__ gamma, const float* __restrict__ beta, int q) {
  float s = 0.f;
#pragma unroll
  for (int nf = 0; nf < 8; nf++) s += a[nf][0] + a[nf][1] + a[nf][2] + a[nf][3];
  s += __shfl_xor(s, 16); s += __shfl_xor(s, 32);
  float mu = s * 0.0078125f;
  float d = 0.f;
#pragma unroll
  for (int nf = 0; nf < 8; nf++)
#pragma unroll
    for (int e = 0; e < 4; e++) { float x = a[nf][e] - mu; d += x * x; }
  d += __shfl_xor(d, 16); d += __shfl_xor(d, 32);
  float rs = rsqrtf(d * 0.0078125f + 1e-5f);
#pragma unroll
  for (int nf = 0; nf < 8; nf++) {
    float4 gg = *(const float4*)&gamma[nf * 16 + q * 4];
    float4 be = *(const float4*)&beta[nf * 16 + q * 4];
    a[nf][0] = (a[nf][0] - mu) * rs * gg.x + be.x;
    a[nf][1] = (a[nf][1] - mu) * rs * gg.y + be.y;
    a[nf][2] = (a[nf][2] - mu) * rs * gg.z + be.z;
    a[nf][3] = (a[nf][3] - mu) * rs * gg.w + be.w;
  }
}

DEVFN void store_row(ushort* __restrict__ out, size_t mrow, const f32x4 a[8], int q) {
#pragma unroll
  for (int nf = 0; nf < 8; nf++)
    *(ushort4*)&out[mrow + nf * 16 + q * 4] = pack4(a[nf]);
}

// ================= fused kernels (512 thr = 8 waves, 32 nodes/wave) =================
// aa input MLP (K=16 pad 32) + LN  ->  m1 (elu, reg-skip, LN) -> Hb
// LDS = 32KB W + 32KB chain = 64KB -> 2 WG/CU.
__global__ __launch_bounds__(512) void fused_aa_kernel(
    const float* __restrict__ h0, int ngrp,
    const ushort* __restrict__ Wp,
    const float* __restrict__ b0, const float* __restrict__ g0, const float* __restrict__ be0,
    const ushort* __restrict__ Wswm1,
    const float* __restrict__ b1, const float* __restrict__ g1, const float* __restrict__ be1,
    ushort* __restrict__ out) {
  __shared__ ushort Wm1[16384];
  __shared__ ushort chain[8 * 2048];  // 8 waves x 4 KB (2 groups)
  int tid = threadIdx.x;
  stage_w(Wswm1, Wm1, tid);
  int lane = tid & 63, wave = tid >> 6;
  int t = lane & 15, q = lane >> 4;
  char* cb0 = (char*)chain + wave * 4096;
  char* cb1 = cb0 + 2048;
  bf16x8 wfa[8];
#pragma unroll
  for (int nf = 0; nf < 8; nf++)
    wfa[nf] = *(const bf16x8*)(Wp + (nf * 16 + t) * 32 + q * 8);
  __syncthreads();

  for (int grp = blockIdx.x; grp < ngrp; grp += gridDim.x) {
    int base = grp * 256 + wave * 32;
    size_t mrow0 = (size_t)(base + t) * H;
    size_t mrow1 = (size_t)(base + 16 + t) * H;

    bf16x8 bf0[2];
#pragma unroll
    for (int g = 0; g < 2; g++) {
      if (q < 2) {
        const float* src = h0 + ((size_t)(base + g * 16 + t) << 4) + (q << 3);
        float4 u0 = *(const float4*)src;
        float4 u1 = *(const float4*)(src + 4);
        bf0[g][0] = (short)f2bf(u0.x); bf0[g][1] = (short)f2bf(u0.y);
        bf0[g][2] = (short)f2bf(u0.z); bf0[g][3] = (short)f2bf(u0.w);
        bf0[g][4] = (short)f2bf(u1.x); bf0[g][5] = (short)f2bf(u1.y);
        bf0[g][6] = (short)f2bf(u1.z); bf0[g][7] = (short)f2bf(u1.w);
      } else {
#pragma unroll
        for (int e = 0; e < 8; e++) bf0[g][e] = 0;
      }
    }
    f32x4 a0[2][8];
#pragma unroll
    for (int g = 0; g < 2; g++)
#pragma unroll
      for (int nf = 0; nf < 8; nf++) a0[g][nf] = (f32x4){0.f, 0.f, 0.f, 0.f};
#pragma unroll
    for (int nf = 0; nf < 8; nf++) {
      a0[0][nf] = __builtin_amdgcn_mfma_f32_16x16x32_bf16(wfa[nf], bf0[0], a0[0][nf], 0, 0, 0);
      a0[1][nf] = __builtin_amdgcn_mfma_f32_16x16x32_bf16(wfa[nf], bf0[1], a0[1][nf], 0, 0, 0);
    }
#pragma unroll
    for (int g = 0; g < 2; g++) {
      bias_act<true>(a0[g], b0, q);
      layernorm(a0[g], g0, be0, q);
    }

    f32x4 a1[2][8];
#pragma unroll
    for (int g = 0; g < 2; g++)
#pragma unroll
      for (int nf = 0; nf < 8; nf++) a1[g][nf] = (f32x4){0.f, 0.f, 0.f, 0.f};
    chained_gemm2(Wm1, cb0, cb1, t, q, a0[0], a0[1], a1[0], a1[1]);
#pragma unroll
    for (int g = 0; g < 2; g++) {
      bias_act<true>(a1[g], b1, q);
      add_reg(a1[g], a0[g]);
      layernorm(a1[g], g1, be1, q);
    }
    store_row(out, mrow0, a1[0], q);
    store_row(out, mrow1, a1[1], q);
  }
}

// cc layer: single GEMM + elu + global skip, 2 groups/wave
__global__ __launch_bounds__(512) void cc_gemm_kernel(
    const ushort* __restrict__ A, int ngrp,
    const ushort* __restrict__ Wsw, const float* __restrict__ bias,
    const ushort* __restrict__ skip, ushort* __restrict__ out) {
  __shared__ ushort Wl[16384];
  int tid = threadIdx.x;
  stage_w(Wsw, Wl, tid);
  int lane = tid & 63, wave = tid >> 6;
  int t = lane & 15, q = lane >> 4;
  __syncthreads();
  for (int grp = blockIdx.x; grp < ngrp; grp += gridDim.x) {
    int base = grp * 256 + wave * 32;
    size_t mrow0 = (size_t)(base + t) * H;
    size_t mrow1 = (size_t)(base + 16 + t) * H;
    bf16x8 bfr[2][4];
    load_bfrag(A, mrow0, q, bfr[0]);
    load_bfrag(A, mrow1, q, bfr[1]);
    ushort4 sk[2][8];
    load_skip_raw(skip, mrow0, q, sk[0]);
    load_skip_raw(skip, mrow1, q, sk[1]);
    f32x4 a[2][8];
#pragma unroll
    for (int g = 0; g < 2; g++)
#pragma unroll
      for (int nf = 0; nf < 8; nf++) a[g][nf] = (f32x4){0.f, 0.f, 0.f, 0.f};
    gemm128_lds2(Wl, bfr[0], bfr[1], a[0], a[1], t, q);
#pragma unroll
    for (int g = 0; g < 2; g++) {
      bias_act<true>(a[g], bias, q);
      add_skip_r(a[g], sk[g]);
    }
    store_row(out, mrow0, a[0], q);
    store_row(out, mrow1, a[1], q);
  }
}

// ca GEMM (elu, +Hb skip) -> m2 (elu, reg-skip, LN) -> final (LN) -> out
// 2 groups/wave; persistent grid; next-tile A-frag prefetch (skip rows load at
// iter start and hide under GEMM-1). LDS = 96KB W + 32KB chain = 128KB.
__global__ __launch_bounds__(512) void fused3_kernel(
    const ushort* __restrict__ A, const ushort* __restrict__ Hbskip, int ngrp,
    const ushort* __restrict__ Wswca, const float* __restrict__ bca,
    const ushort* __restrict__ Wswm2, const float* __restrict__ bm2,
    const float* __restrict__ gm2, const float* __restrict__ bem2,
    const ushort* __restrict__ Wswf, const float* __restrict__ bf,
    const float* __restrict__ gf, const float* __restrict__ bef,
    ushort* __restrict__ out) {
  __shared__ ushort Wca[16384], Wm2[16384], Wf[16384];
  __shared__ ushort chain[8 * 2048];
  int tid = threadIdx.x;
  stage_w(Wswca, Wca, tid);
  stage_w(Wswm2, Wm2, tid);
  stage_w(Wswf, Wf, tid);
  int lane = tid & 63, wave = tid >> 6;
  int t = lane & 15, q = lane >> 4;
  char* cb0 = (char*)chain + wave * 4096;
  char* cb1 = cb0 + 2048;

  int grp = blockIdx.x;
  bf16x8 bfr[2][4];
  if (grp < ngrp) {
    int base = grp * 256 + wave * 32;
    load_bfrag(A, (size_t)(base + t) * H, q, bfr[0]);
    load_bfrag(A, (size_t)(base + 16 + t) * H, q, bfr[1]);
  }
  __syncthreads();

  for (; grp < ngrp;) {
    int nxt = grp + gridDim.x;
    bf16x8 nbfr[2][4];
    if (nxt < ngrp) {  // prefetch next tile's A fragments
      int nb = nxt * 256 + wave * 32;
      load_bfrag(A, (size_t)(nb + t) * H, q, nbfr[0]);
      load_bfrag(A, (size_t)(nb + 16 + t) * H, q, nbfr[1]);
    }
    int base = grp * 256 + wave * 32;
    size_t mrow0 = (size_t)(base + t) * H;
    size_t mrow1 = (size_t)(base + 16 + t) * H;
    ushort4 sk[2][8];
    load_skip_raw(Hbskip, mrow0, q, sk[0]);  // latency hides under GEMM-1
    load_skip_raw(Hbskip, mrow1, q, sk[1]);

    f32x4 a1[2][8];
#pragma unroll
    for (int g = 0; g < 2; g++)
#pragma unroll
      for (int nf = 0; nf < 8; nf++) a1[g][nf] = (f32x4){0.f, 0.f, 0.f, 0.f};
    gemm128_lds2(Wca, bfr[0], bfr[1], a1[0], a1[1], t, q);
#pragma unroll
    for (int g = 0; g < 2; g++) {
      bias_act<true>(a1[g], bca, q);
      add_skip_r(a1[g], sk[g]);
    }

    f32x4 a2[2][8];
#pragma unroll
    for (int g = 0; g < 2; g++)
#pragma unroll
      for (int nf = 0; nf < 8; nf++) a2[g][nf] = (f32x4){0.f, 0.f, 0.f, 0.f};
    chained_gemm2(Wm2, cb0, cb1, t, q, a1[0], a1[1], a2[0], a2[1]);
#pragma unroll
    for (int g = 0; g < 2; g++) {
      bias_act<true>(a2[g], bm2, q);
      add_reg(a2[g], a1[g]);
      layernorm(a2[g], gm2, bem2, q);
    }

    f32x4 a3[2][8];
#pragma unroll
    for (int g = 0; g < 2; g++)
#pragma unroll
      for (int nf = 0; nf < 8; nf++) a3[g][nf] = (f32x4){0.f, 0.f, 0.f, 0.f};
    chained_gemm2(Wf, cb0, cb1, t, q, a2[0], a2[1], a3[0], a3[1]);
#pragma unroll
    for (int g = 0; g < 2; g++) {
      bias_act<false>(a3[g], bf, q);
      layernorm(a3[g], gf, bef, q);
    }
    store_row(out, mrow0, a3[0], q);
    store_row(out, mrow1, a3[1], q);

    grp = nxt;
#pragma unroll
    for (int g = 0; g < 2; g++)
#pragma unroll
      for (int ks = 0; ks < 4; ks++) bfr[g][ks] = nbfr[g][ks];
  }
}

// ================= VALU GEMM for the cg input MLP (K=32, fp32 in) =================
template<int K, bool ACT, bool LN>
__global__ __launch_bounds__(512) void gemm_fused(
    const float* __restrict__ Av, int ntiles,
    const float* __restrict__ W, const float* __restrict__ bias,
    const float* __restrict__ gamma, const float* __restrict__ beta,
    ushort* __restrict__ out) {
  constexpr int AS = K + 4;
  constexpr int KM = K - 1;
  constexpr int F4R = K / 4;
  __shared__ float Wl[K * H];
  __shared__ float Al[128 * AS];
  int tid = threadIdx.x;

  for (int q = tid; q < K * H / 4; q += 512)
    *(float4*)&Wl[q * 4] = *(const float4*)&W[q * 4];

  int tc = tid & 31, tr = tid >> 5;
  const int rot = (4 * tr) & KM;
  const int c = 4 * tc;
  const float* aBase = Al + (tr * 8) * AS;

  for (int tile = blockIdx.x; tile < ntiles; tile += gridDim.x) {
    int r0 = tile * 128;
    __syncthreads();
    for (int q = tid; q < 128 * F4R; q += 512) {
      int r = q / F4R, cc = (q % F4R) * 4;
      float4 v = *(const float4*)(Av + (size_t)(r0 + r) * K + cc);
      int rr = (4 * (r >> 3)) & KM;
      *(float4*)&Al[r * AS + ((cc + rr) & KM)] = v;
    }
    __syncthreads();

    float4 acc[8];
#pragma unroll
    for (int i = 0; i < 8; i++) acc[i] = make_float4(0.f, 0.f, 0.f, 0.f);

#pragma unroll 2
    for (int k = 0; k < K; k += 4) {
      int kp = (k + rot) & KM;
      float4 av[8];
#pragma unroll
      for (int r8 = 0; r8 < 8; r8++) av[r8] = *(const float4*)(aBase + r8 * AS + kp);
      float4 w0 = *(const float4*)&Wl[(k + 0) * H + c];
      float4 w1 = *(const float4*)&Wl[(k + 1) * H + c];
      float4 w2 = *(const float4*)&Wl[(k + 2) * H + c];
      float4 w3 = *(const float4*)&Wl[(k + 3) * H + c];
#pragma unroll
      for (int r8 = 0; r8 < 8; r8++) {
        float4 a = av[r8];
        fma4(acc[r8], a.x, w0); fma4(acc[r8], a.y, w1);
        fma4(acc[r8], a.z, w2); fma4(acc[r8], a.w, w3);
      }
    }

    float4 bA = *(const float4*)&bias[c];
    float4 gA, beA;
    if constexpr (LN) {
      gA = *(const float4*)&gamma[c];
      beA = *(const float4*)&beta[c];
    }
#pragma unroll
    for (int r8 = 0; r8 < 8; r8++) {
      int r = tr * 8 + r8;
      size_t grow = (size_t)(r0 + r) * H;
      float4 v;
      v.x = acc[r8].x + bA.x; v.y = acc[r8].y + bA.y;
      v.z = acc[r8].z + bA.z; v.w = acc[r8].w + bA.w;
      if constexpr (ACT) {
        v.x = elu(v.x); v.y = elu(v.y); v.z = elu(v.z); v.w = elu(v.w);
      }
      if constexpr (LN) {
        float s = v.x + v.y + v.z + v.w;
        s += __shfl_xor(s, 1); s += __shfl_xor(s, 2);
        s += __shfl_xor(s, 4); s += __shfl_xor(s, 8); s += __shfl_xor(s, 16);
        float mu = s * 0.0078125f;
        float t, d;
        t = v.x - mu; d = t * t;  t = v.y - mu; d += t * t;
        t = v.z - mu; d += t * t; t = v.w - mu; d += t * t;
        d += __shfl_xor(d, 1); d += __shfl_xor(d, 2);
        d += __shfl_xor(d, 4); d += __shfl_xor(d, 8); d += __shfl_xor(d, 16);
        float rs = rsqrtf(d * 0.0078125f + 1e-5f);
        v.x = (v.x - mu) * rs * gA.x + beA.x; v.y = (v.y - mu) * rs * gA.y + beA.y;
        v.z = (v.z - mu) * rs * gA.z + beA.z; v.w = (v.w - mu) * rs * gA.w + beA.w;
      }
      *(ushort4*)&out[grow + c] = make_ushort4(f2bf(v.x), f2bf(v.y), f2bf(v.z), f2bf(v.w));
    }
  }
}

// ================= pooling =================
__global__ __launch_bounds__(128) void pool_sum_kernel(const ushort* __restrict__ h,
                                                       const int* __restrict__ gid,
                                                       float* __restrict__ sums) {
  int f = threadIdx.x;
  int chunk = N_AA / gridDim.x;
  int start = blockIdx.x * chunk, end = start + chunk;
  int g = gid[start];
  float acc = 0.f;
  for (int i = start; i < end; ++i) {
    int gi = gid[i];
    if (gi != g) { atomicAdd(&sums[g * H + f], acc); acc = 0.f; g = gi; }
    acc += bf2f(h[(size_t)i * H + f]);
  }
  atomicAdd(&sums[g * H + f], acc);
}

__global__ void pool_final_kernel(const float* __restrict__ sums, const int* __restrict__ counts,
                                  float* __restrict__ out) {
  int b = blockIdx.x, f = threadIdx.x;
  float c = (float)counts[b];
  out[b * H + f] = sums[b * H + f] / fmaxf(c, 1.f);
  if (f == 0) out[B_GR * H + b] = c;
}

// ================= launch =================
extern "C" void kernel_launch(void* const* d_in, const int* in_sizes, int n_in,
                              void* d_out, int out_size, void* d_ws, size_t ws_size,
                              hipStream_t stream) {
  (void)in_sizes; (void)n_in; (void)out_size; (void)ws_size;
  const float* h_aa0 = (const float*)d_in[0];
  const float* h_cg0 = (const float*)d_in[1];
  const int* src_cc = (const int*)d_in[2];
  const int* dst_cc = (const int*)d_in[3];
  const int* src_ca = (const int*)d_in[4];
  const int* dst_ca = (const int*)d_in[5];
  // d_in[6], d_in[7] (src_ac/dst_ac): dead in the reference — outputs depend only on h_aa
  const int* graph_id = (const int*)d_in[8];
  const float* W_cg0 = (const float*)d_in[9];
  const float* b_cg0 = (const float*)d_in[10];
  const float* g_cg0 = (const float*)d_in[11];
  const float* be_cg0 = (const float*)d_in[12];
  const float* W_aa0 = (const float*)d_in[13];
  const float* b_aa0 = (const float*)d_in[14];
  const float* g_aa0 = (const float*)d_in[15];
  const float* be_aa0 = (const float*)d_in[16];
  const float* W_cc = (const float*)d_in[17];
  const float* b_cc = (const float*)d_in[18];
  const float* W_m1 = (const float*)d_in[19];
  const float* b_m1 = (const float*)d_in[20];
  const float* g_m1 = (const float*)d_in[21];
  const float* be_m1 = (const float*)d_in[22];
  const float* W_ca = (const float*)d_in[23];
  const float* b_ca = (const float*)d_in[24];
  const float* W_m2 = (const float*)d_in[25];
  const float* b_m2 = (const float*)d_in[26];
  const float* g_m2 = (const float*)d_in[27];
  const float* be_m2 = (const float*)d_in[28];
  // d_in[29], d_in[30] (W_ac/b_ac): dead
  const float* W_f = (const float*)d_in[31];
  const float* b_f = (const float*)d_in[32];
  const float* g_f = (const float*)d_in[33];
  const float* be_f = (const float*)d_in[34];

  char* ws = (char*)d_ws;
  size_t off = 0;
  auto alloc = [&](size_t bytes) -> void* {
    void* p = ws + off;
    off = (off + bytes + 255) & ~(size_t)255;
    return p;
  };
  ushort* cgA = (ushort*)alloc((size_t)N_CG * H * 2);
  ushort* G   = (ushort*)alloc((size_t)N_CG * H * 2);
  ushort* Hb  = (ushort*)alloc((size_t)N_AA * H * 2);
  ushort* AGG = (ushort*)alloc((size_t)N_AA * H * 2);
  int* cnt_s_cc = (int*)alloc((size_t)N_CG * 4);  // contiguous 4-array block (one memset, one deg)
  int* cnt_d_cc = (int*)alloc((size_t)N_CG * 4);
  int* cnt_s_ca = (int*)alloc((size_t)N_CG * 4);
  int* cnt_d_ca = (int*)alloc((size_t)N_AA * 4);
  float* dout_cc = (float*)alloc((size_t)N_CG * 4);  // contiguous, same order as counts
  float* din_cc  = (float*)alloc((size_t)N_CG * 4);
  float* dout_ca = (float*)alloc((size_t)N_CG * 4);
  float* din_ca  = (float*)alloc((size_t)N_AA * 4);
  int* offs_cc = (int*)alloc((size_t)N_CG * 4);
  int* cur_cc  = (int*)alloc((size_t)N_CG * 4);
  int* offs_ca = (int*)alloc((size_t)N_AA * 4);
  int* cur_ca  = (int*)alloc((size_t)N_AA * 4);
  int* sorted_cc = (int*)alloc((size_t)E_CC * 4);
  int* sorted_ca = (int*)alloc((size_t)E_CA * 4);
  int* bsum = (int*)alloc(320 * 4);
  float* sums = (float*)alloc((size_t)B_GR * H * 4);
  int* counts = (int*)alloc(256);
  ushort* Wsw_cc = (ushort*)alloc(H * H * 2);
  ushort* Wsw_m1 = (ushort*)alloc(H * H * 2);
  ushort* Wsw_ca = (ushort*)alloc(H * H * 2);
  ushort* Wsw_m2 = (ushort*)alloc(H * H * 2);
  ushort* Wsw_f  = (ushort*)alloc(H * H * 2);
  ushort* Wp_aa  = (ushort*)alloc(H * 32 * 2);

  hipMemsetAsync(cnt_s_cc, 0, (size_t)(3 * N_CG + N_AA) * 4, stream);
  hipMemsetAsync(sums, 0, (size_t)B_GR * H * 4, stream);

  // prep: weights, histograms, graph counts, degrees
  wprep_kernel<<<336, 256, 0, stream>>>(W_cc, W_m1, W_ca, W_m2, W_f,
                                        Wsw_cc, Wsw_m1, Wsw_ca, Wsw_m2, Wsw_f,
                                        W_aa0, Wp_aa);
  hist4_kernel<<<2048, 256, 0, stream>>>(src_cc, dst_cc, src_ca, dst_ca,
                                         cnt_s_cc, cnt_d_cc, cnt_s_ca, cnt_d_ca);
  graph_count_kernel<<<1, 64, 0, stream>>>(graph_id, N_AA, counts);
  deg_all_kernel<<<(3 * N_CG + N_AA) / 256, 256, 0, stream>>>(cnt_s_cc, dout_cc);

  // CSR build (cc + ca merged)
  scan1_kernel<<<320, 256, 0, stream>>>(cnt_d_cc, offs_cc, cnt_d_ca, offs_ca, bsum);
  scan2_kernel<<<2, 256, 0, stream>>>(bsum);
  scan3_kernel<<<(N_CG + N_AA) / 256, 256, 0, stream>>>(offs_cc, cur_cc, offs_ca, cur_ca, bsum);
  place2_kernel<<<2048, 256, 0, stream>>>(src_cc, dst_cc, src_ca, dst_ca,
                                          cur_cc, sorted_cc, cur_ca, sorted_ca);

  // cg input MLP (VALU, fp32 in)
  gemm_fused<32, true, true><<<N_CG / 128, 512, 0, stream>>>(
      h_cg0, N_CG / 128, W_cg0, b_cg0, g_cg0, be_cg0, cgA);

  // aa input MLP + m1 fused -> Hb (64KB LDS -> 2 WG/CU; grid 1024)
  fused_aa_kernel<<<1024, 512, 0, stream>>>(
      h_aa0, N_AA / 256, Wp_aa, b_aa0, g_aa0, be_aa0,
      Wsw_m1, b_m1, g_m1, be_m1, Hb);

  // cg_to_cg conv: gather + GEMM(+elu) + skip(cgA) -> G
  gather_kernel<<<N_CG / 8, 256, 0, stream>>>(cgA, sorted_cc, offs_cc, cnt_d_cc, dout_cc, din_cc, G, N_CG);
  cc_gemm_kernel<<<N_CG / 256, 512, 0, stream>>>(G, N_CG / 256, Wsw_cc, b_cc, cgA, G);

  // cg_to_aa gather -> AGG, then fused ca+m2+final in-place on AGG
  gather_kernel<<<N_AA / 8, 256, 0, stream>>>(G, sorted_ca, offs_ca, cnt_d_ca, dout_ca, din_ca, AGG, N_AA);
  // 256 persistent blocks, 4 iters, A-frag prefetch
  fused3_kernel<<<256, 512, 0, stream>>>(
      AGG, Hb, N_AA / 256,
      Wsw_ca, b_ca, Wsw_m2, b_m2, g_m2, be_m2,
      Wsw_f, b_f, g_f, be_f, AGG);

  // mean pool per graph
  pool_sum_kernel<<<1024, 128, 0, stream>>>(AGG, graph_id, sums);
  pool_final_kernel<<<B_GR, 128, 0, stream>>>(sums, counts, (float*)d_out);
}

// Round 10
// 422.387 us; speedup vs baseline: 1.3250x; 1.3250x over previous
//
#include <hip/hip_runtime.h>

using ushort = unsigned short;

#define DEVFN static __device__ __forceinline__

constexpr int H = 128;
constexpr int N_AA = 262144, N_CG = 65536;
constexpr int E_CC = 262144, E_CA = 524288;
constexpr int B_GR = 64;

typedef __attribute__((ext_vector_type(8))) short bf16x8;
typedef __attribute__((ext_vector_type(4))) float f32x4;

DEVFN float elu(float x) { return x > 0.f ? x : __expf(x) - 1.f; }

DEVFN float bf2f(ushort s) { return __uint_as_float(((unsigned)s) << 16); }
DEVFN ushort f2bf(float f) {
  unsigned u = __float_as_uint(f);
  return (ushort)((u + 0x7FFFu + ((u >> 16) & 1u)) >> 16);
}
DEVFN ushort4 pack4(const f32x4& a) {
  return make_ushort4(f2bf(a[0]), f2bf(a[1]), f2bf(a[2]), f2bf(a[3]));
}

DEVFN void fma4(float4& c, float a, float4 w) {
  c.x += a * w.x; c.y += a * w.y; c.z += a * w.z; c.w += a * w.w;
}

// ================= graph prep (merged kernels) =================
__global__ void hist4_kernel(const int* __restrict__ src_cc, const int* __restrict__ dst_cc,
                             const int* __restrict__ src_ca, const int* __restrict__ dst_ca,
                             int* __restrict__ c_scc, int* __restrict__ c_dcc,
                             int* __restrict__ c_sca, int* __restrict__ c_dca) {
  int i = blockIdx.x * blockDim.x + threadIdx.x;
  int stride = gridDim.x * blockDim.x;
  const int T = 2 * E_CC + 2 * E_CA;
  for (; i < T; i += stride) {
    const int* a; int* c; int j = i;
    if (j < E_CC) { a = src_cc; c = c_scc; }
    else if (j < 2 * E_CC) { a = dst_cc; c = c_dcc; j -= E_CC; }
    else if (j < 2 * E_CC + E_CA) { a = src_ca; c = c_sca; j -= 2 * E_CC; }
    else { a = dst_ca; c = c_dca; j -= 2 * E_CC + E_CA; }
    atomicAdd(&c[a[j]], 1);
  }
}

// graph_id is SORTED -> per-graph counts via binary-search boundaries (no atomics)
__global__ void graph_count_kernel(const int* __restrict__ gid, int n, int* __restrict__ counts) {
  int b = threadIdx.x;
  auto lb = [&](int v) {
    int lo = 0, hi = n;
    while (lo < hi) { int m = (lo + hi) >> 1; if (gid[m] < v) lo = m + 1; else hi = m; }
    return lo;
  };
  int s = lb(b), e = lb(b + 1);
  counts[b] = e - s;
}

// all 4 degree arrays (counts and outputs laid out contiguously, same order)
__global__ void deg_all_kernel(const int* __restrict__ cnt, float* __restrict__ d) {
  int i = blockIdx.x * blockDim.x + threadIdx.x;
  int c = cnt[i]; if (c < 1) c = 1;
  d[i] = rsqrtf((float)c);
}

// 5x W swizzle + 1x W_aa0 pad in one launch.
// Wsw[r*128+j] = bf16(W[k][r]), k = (j - (r&15)*8) & 127  (matches LDS read swizzle)
__global__ void wprep_kernel(const float* __restrict__ w0, const float* __restrict__ w1,
                             const float* __restrict__ w2, const float* __restrict__ w3,
                             const float* __restrict__ w4,
                             ushort* __restrict__ o0, ushort* __restrict__ o1,
                             ushort* __restrict__ o2, ushort* __restrict__ o3,
                             ushort* __restrict__ o4,
                             const float* __restrict__ wa, ushort* __restrict__ oa) {
  int idx = blockIdx.x * 256 + threadIdx.x;  // grid 336*256
  if (idx < 81920) {
    int which = idx >> 14, id = idx & 16383;
    const float* W = which == 0 ? w0 : which == 1 ? w1 : which == 2 ? w2 : which == 3 ? w3 : w4;
    ushort* O = which == 0 ? o0 : which == 1 ? o1 : which == 2 ? o2 : which == 3 ? o3 : o4;
    int r = id >> 7, j = id & 127;
    int k = (j - ((r & 15) << 3)) & 127;
    O[id] = f2bf(W[k * 128 + r]);
  } else if (idx < 86016) {
    int id = idx - 81920;
    int n = id >> 5, k = id & 31;
    oa[id] = (k < 16) ? f2bf(wa[k * 128 + n]) : (ushort)0;
  }
}

// merged exclusive scans (cc: 64 blocks, ca: 256 blocks; bsum = 320 ints)
__global__ void scan1_kernel(const int* __restrict__ in_cc, int* __restrict__ out_cc,
                             const int* __restrict__ in_ca, int* __restrict__ out_ca,
                             int* __restrict__ bsum) {
  __shared__ int l[256];
  int b = blockIdx.x, tid = threadIdx.x;
  const int* in; int* out; int bi;
  if (b < 64) { in = in_cc; out = out_cc; bi = b; } else { in = in_ca; out = out_ca; bi = b - 64; }
  int base = bi * 1024 + tid * 4;
  int4 v = *(const int4*)&in[base];
  int s = v.x + v.y + v.z + v.w;
  l[tid] = s; __syncthreads();
  for (int off = 1; off < 256; off <<= 1) {
    int t = (tid >= off) ? l[tid - off] : 0;
    __syncthreads();
    if (tid >= off) l[tid] += t;
    __syncthreads();
  }
  int excl = l[tid] - s;
  if (tid == 255) bsum[b] = l[255];
  int4 o; o.x = excl; o.y = o.x + v.x; o.z = o.y + v.y; o.w = o.z + v.z;
  *(int4*)&out[base] = o;
}

__global__ void scan2_kernel(int* __restrict__ bsum) {
  __shared__ int l[256];
  int b = blockIdx.x, tid = threadIdx.x;
  int* bs = bsum + (b ? 64 : 0);
  int nb = b ? 256 : 64;
  int v = (tid < nb) ? bs[tid] : 0;
  l[tid] = v; __syncthreads();
  for (int off = 1; off < 256; off <<= 1) {
    int t = (tid >= off) ? l[tid - off] : 0;
    __syncthreads();
    if (tid >= off) l[tid] += t;
    __syncthreads();
  }
  if (tid < nb) bs[tid] = l[tid] - v;
}

__global__ void scan3_kernel(int* __restrict__ offs_cc, int* __restrict__ cur_cc,
                             int* __restrict__ offs_ca, int* __restrict__ cur_ca,
                             const int* __restrict__ bsum) {
  int i = blockIdx.x * blockDim.x + threadIdx.x;
  if (i < N_CG) {
    int o = offs_cc[i] + bsum[i >> 10];
    offs_cc[i] = o; cur_cc[i] = o;
  } else if (i < N_CG + N_AA) {
    int j = i - N_CG;
    int o = offs_ca[j] + bsum[64 + (j >> 10)];
    offs_ca[j] = o; cur_ca[j] = o;
  }
}

__global__ void place2_kernel(const int* __restrict__ src_cc, const int* __restrict__ dst_cc,
                              const int* __restrict__ src_ca, const int* __restrict__ dst_ca,
                              int* __restrict__ cur_cc, int* __restrict__ sorted_cc,
                              int* __restrict__ cur_ca, int* __restrict__ sorted_ca) {
  int i = blockIdx.x * blockDim.x + threadIdx.x;
  int stride = gridDim.x * blockDim.x;
  for (; i < E_CC + E_CA; i += stride) {
    if (i < E_CC) {
      int d = dst_cc[i];
      int slot = atomicAdd(&cur_cc[d], 1);
      sorted_cc[slot] = src_cc[i];
    } else {
      int j = i - E_CC;
      int d = dst_ca[j];
      int slot = atomicAdd(&cur_ca[d], 1);
      sorted_ca[slot] = src_ca[j];
    }
  }
}

// ================= MFMA building blocks =================
// Per-wave 16-node groups. C/D layout (mfma_f32_16x16x32_bf16): lane(t=lane&15,
// q=lane>>4) owns node t, feats nf*16+q*4+{0..3}. B-frag: node t feats [ks*32+q*8,+8).

DEVFN void stage_w(const ushort* __restrict__ g, ushort* l, int tid) {
  for (int i = tid; i < 2048; i += 512)  // 32 KB
    *((uint4*)l + i) = *((const uint4*)g + i);
}

DEVFN void load_skip_raw(const ushort* __restrict__ skip, size_t mrow, int q, ushort4 sk[8]) {
#pragma unroll
  for (int nf = 0; nf < 8; nf++)
    sk[nf] = *(const ushort4*)&skip[mrow + nf * 16 + q * 4];
}

// CSR gather directly into B-frag: bfr[ks] = bf16(di * sum_e dout[s]*h[s][ks*32+q*8..+8))
DEVFN void gather_bfrag(const ushort* __restrict__ h, const int* __restrict__ sorted,
                        int o, int c, const float* __restrict__ dout, float di,
                        int q, bf16x8 bfr[4]) {
  float acc[4][8];
#pragma unroll
  for (int ks = 0; ks < 4; ks++)
#pragma unroll
    for (int j = 0; j < 8; j++) acc[ks][j] = 0.f;
  for (int e = o; e < o + c; ++e) {
    int s = sorted[e];
    float w = dout[s];
    const ushort* row = h + (size_t)s * H + q * 8;
#pragma unroll
    for (int ks = 0; ks < 4; ks++) {
      bf16x8 v = *(const bf16x8*)(row + ks * 32);
#pragma unroll
      for (int j = 0; j < 8; j++) acc[ks][j] += w * bf2f((ushort)v[j]);
    }
  }
#pragma unroll
  for (int ks = 0; ks < 4; ks++)
#pragma unroll
    for (int j = 0; j < 8; j++) bfr[ks][j] = (short)f2bf(acc[ks][j] * di);
}

// swizzled-LDS 128x128 GEMM accumulate (32 MFMA), one group
DEVFN void gemm128_lds(const ushort* __restrict__ Wlds, const bf16x8 bfr[4], f32x4 acc[8], int t, int q) {
#pragma unroll
  for (int ks = 0; ks < 4; ks++) {
    int coff = (ks * 64 + q * 16 + t * 16) & 255;
#pragma unroll
    for (int nf = 0; nf < 8; nf++) {
      bf16x8 wv = *(const bf16x8*)((const char*)Wlds + (nf * 16 + t) * 256 + coff);
      acc[nf] = __builtin_amdgcn_mfma_f32_16x16x32_bf16(wv, bfr[ks], acc[nf], 0, 0, 0);
    }
  }
}

// swizzled-LDS 128x128 GEMM, 2 node-groups sharing each W read (32 reads, 64 MFMA)
DEVFN void gemm128_lds2(const ushort* __restrict__ Wlds,
                        const bf16x8 b0[4], const bf16x8 b1[4],
                        f32x4 A0[8], f32x4 A1[8], int t, int q) {
#pragma unroll
  for (int ks = 0; ks < 4; ks++) {
    int coff = (ks * 64 + q * 16 + t * 16) & 255;
#pragma unroll
    for (int nf = 0; nf < 8; nf++) {
      bf16x8 wv = *(const bf16x8*)((const char*)Wlds + (nf * 16 + t) * 256 + coff);
      A0[nf] = __builtin_amdgcn_mfma_f32_16x16x32_bf16(wv, b0[ks], A0[nf], 0, 0, 0);
      A1[nf] = __builtin_amdgcn_mfma_f32_16x16x32_bf16(wv, b1[ks], A1[nf], 0, 0, 0);
    }
  }
}

// chained GEMM, single group: C-layout regs -> 2KB wave-private LDS -> B-frags -> MFMA
DEVFN void chained_gemm(const ushort* __restrict__ Wlds, char* cbb, int t, int q,
                        const f32x4 ain[8], f32x4 acc[8]) {
  const int tb = t * 8;
  char* row = cbb + t * 128;
#pragma unroll
  for (int half = 0; half < 2; half++) {
    asm volatile("s_waitcnt lgkmcnt(0)" ::: "memory");
#pragma unroll
    for (int nfl = 0; nfl < 4; nfl++) {
      int off = (nfl * 32 + q * 8 + tb) & 127;
      *(ushort4*)(row + off) = pack4(ain[half * 4 + nfl]);
    }
    asm volatile("s_waitcnt lgkmcnt(0)" ::: "memory");
#pragma unroll
    for (int ksl = 0; ksl < 2; ksl++) {
      int ks = half * 2 + ksl;
      uint2 lo = *(const uint2*)(row + ((ksl * 64 + q * 16 + tb) & 127));
      uint2 hi = *(const uint2*)(row + ((ksl * 64 + q * 16 + 8 + tb) & 127));
      union { uint4 u; bf16x8 v; } b;
      b.u = make_uint4(lo.x, lo.y, hi.x, hi.y);
      int coff = (ks * 64 + q * 16 + t * 16) & 255;
#pragma unroll
      for (int nf = 0; nf < 8; nf++) {
        bf16x8 wv = *(const bf16x8*)((const char*)Wlds + (nf * 16 + t) * 256 + coff);
        acc[nf] = __builtin_amdgcn_mfma_f32_16x16x32_bf16(wv, b.v, acc[nf], 0, 0, 0);
      }
    }
  }
}

// chained GEMM, 2 groups sharing W reads
DEVFN void chained_gemm2(const ushort* __restrict__ Wlds, char* cb0, char* cb1,
                         int t, int q,
                         const f32x4 i0[8], const f32x4 i1[8],
                         f32x4 A0[8], f32x4 A1[8]) {
  const int tb = t * 8;
  char* row0 = cb0 + t * 128;
  char* row1 = cb1 + t * 128;
#pragma unroll
  for (int half = 0; half < 2; half++) {
    asm volatile("s_waitcnt lgkmcnt(0)" ::: "memory");
#pragma unroll
    for (int nfl = 0; nfl < 4; nfl++) {
      int off = (nfl * 32 + q * 8 + tb) & 127;
      *(ushort4*)(row0 + off) = pack4(i0[half * 4 + nfl]);
      *(ushort4*)(row1 + off) = pack4(i1[half * 4 + nfl]);
    }
    asm volatile("s_waitcnt lgkmcnt(0)" ::: "memory");
#pragma unroll
    for (int ksl = 0; ksl < 2; ksl++) {
      int ks = half * 2 + ksl;
      int olo = (ksl * 64 + q * 16 + tb) & 127;
      int ohi = (ksl * 64 + q * 16 + 8 + tb) & 127;
      uint2 lo0 = *(const uint2*)(row0 + olo);
      uint2 hi0 = *(const uint2*)(row0 + ohi);
      uint2 lo1 = *(const uint2*)(row1 + olo);
      uint2 hi1 = *(const uint2*)(row1 + ohi);
      union { uint4 u; bf16x8 v; } b0, b1;
      b0.u = make_uint4(lo0.x, lo0.y, hi0.x, hi0.y);
      b1.u = make_uint4(lo1.x, lo1.y, hi1.x, hi1.y);
      int coff = (ks * 64 + q * 16 + t * 16) & 255;
#pragma unroll
      for (int nf = 0; nf < 8; nf++) {
        bf16x8 wv = *(const bf16x8*)((const char*)Wlds + (nf * 16 + t) * 256 + coff);
        A0[nf] = __builtin_amdgcn_mfma_f32_16x16x32_bf16(wv, b0.v, A0[nf], 0, 0, 0);
        A1[nf] = __builtin_amdgcn_mfma_f32_16x16x32_bf16(wv, b1.v, A1[nf], 0, 0, 0);
      }
    }
  }
}

template<bool ACT>
DEVFN void bias_act(f32x4 a[8], const float* __restrict__ bias, int q) {
#pragma unroll
  for (int nf = 0; nf < 8; nf++) {
    float4 bb = *(const float4*)&bias[nf * 16 + q * 4];
    a[nf][0] += bb.x; a[nf][1] += bb.y; a[nf][2] += bb.z; a[nf][3] += bb.w;
    if constexpr (ACT) {
#pragma unroll
      for (int e = 0; e < 4; e++) a[nf][e] = elu(a[nf][e]);
    }
  }
}

DEVFN void add_reg(f32x4 a[8], const f32x4 b[8]) {
#pragma unroll
  for (int nf = 0; nf < 8; nf++)
#pragma unroll
    for (int e = 0; e < 4; e++) a[nf][e] += b[nf][e];
}

DEVFN void add_skip_r(f32x4 a[8], const ushort4 sk[8]) {
#pragma unroll
  for (int nf = 0; nf < 8; nf++) {
    a[nf][0] += bf2f(sk[nf].x); a[nf][1] += bf2f(sk[nf].y);
    a[nf][2] += bf2f(sk[nf].z); a[nf][3] += bf2f(sk[nf].w);
  }
}

DEVFN void layernorm(f32x4 a[8], const float* __restrict__ gamma, const float* __restrict__ beta, int q) {
  float s = 0.f;
#pragma unroll
  for (int nf = 0; nf < 8; nf++) s += a[nf][0] + a[nf][1] + a[nf][2] + a[nf][3];
  s += __shfl_xor(s, 16); s += __shfl_xor(s, 32);
  float mu = s * 0.0078125f;
  float d = 0.f;
#pragma unroll
  for (int nf = 0; nf < 8; nf++)
#pragma unroll
    for (int e = 0; e < 4; e++) { float x = a[nf][e] - mu; d += x * x; }
  d += __shfl_xor(d, 16); d += __shfl_xor(d, 32);
  float rs = rsqrtf(d * 0.0078125f + 1e-5f);
#pragma unroll
  for (int nf = 0; nf < 8; nf++) {
    float4 gg = *(const float4*)&gamma[nf * 16 + q * 4];
    float4 be = *(const float4*)&beta[nf * 16 + q * 4];
    a[nf][0] = (a[nf][0] - mu) * rs * gg.x + be.x;
    a[nf][1] = (a[nf][1] - mu) * rs * gg.y + be.y;
    a[nf][2] = (a[nf][2] - mu) * rs * gg.z + be.z;
    a[nf][3] = (a[nf][3] - mu) * rs * gg.w + be.w;
  }
}

DEVFN void store_row(ushort* __restrict__ out, size_t mrow, const f32x4 a[8], int q) {
#pragma unroll
  for (int nf = 0; nf < 8; nf++)
    *(ushort4*)&out[mrow + nf * 16 + q * 4] = pack4(a[nf]);
}

// ================= fused kernels =================
// aa input MLP (K=16 pad 32) + LN -> m1 (elu, reg-skip, LN) -> Hb.
// Round-8 proven single-group form: 512 thr, persistent, input prefetch.
__global__ __launch_bounds__(512) void fused_aa_kernel(
    const float* __restrict__ h0, int ngrp,
    const ushort* __restrict__ Wp,
    const float* __restrict__ b0, const float* __restrict__ g0, const float* __restrict__ be0,
    const ushort* __restrict__ Wswm1,
    const float* __restrict__ b1, const float* __restrict__ g1, const float* __restrict__ be1,
    ushort* __restrict__ out) {
  __shared__ ushort Wm1[16384];
  __shared__ ushort chain[8 * 1024];  // 8 waves x 2 KB
  int tid = threadIdx.x;
  stage_w(Wswm1, Wm1, tid);
  int lane = tid & 63, wave = tid >> 6;
  int t = lane & 15, q = lane >> 4;
  char* cbb = (char*)chain + wave * 2048;
  bf16x8 wfa[8];
#pragma unroll
  for (int nf = 0; nf < 8; nf++)
    wfa[nf] = *(const bf16x8*)(Wp + (nf * 16 + t) * 32 + q * 8);

  int grp = blockIdx.x;
  float4 c0, c1;
  if (grp < ngrp && q < 2) {
    const float* src = h0 + ((size_t)(grp * 128 + wave * 16 + t) << 4) + (q << 3);
    c0 = *(const float4*)src; c1 = *(const float4*)(src + 4);
  }
  __syncthreads();

  for (; grp < ngrp;) {
    int nxt = grp + gridDim.x;
    float4 n0, n1;
    if (nxt < ngrp && q < 2) {
      const float* src = h0 + ((size_t)(nxt * 128 + wave * 16 + t) << 4) + (q << 3);
      n0 = *(const float4*)src; n1 = *(const float4*)(src + 4);
    }
    size_t mrow = (size_t)(grp * 128 + wave * 16 + t) * H;
    bf16x8 bf0;
    if (q < 2) {
      bf0[0] = (short)f2bf(c0.x); bf0[1] = (short)f2bf(c0.y);
      bf0[2] = (short)f2bf(c0.z); bf0[3] = (short)f2bf(c0.w);
      bf0[4] = (short)f2bf(c1.x); bf0[5] = (short)f2bf(c1.y);
      bf0[6] = (short)f2bf(c1.z); bf0[7] = (short)f2bf(c1.w);
    } else {
#pragma unroll
      for (int e = 0; e < 8; e++) bf0[e] = 0;
    }
    f32x4 a0[8];
#pragma unroll
    for (int nf = 0; nf < 8; nf++) a0[nf] = (f32x4){0.f, 0.f, 0.f, 0.f};
#pragma unroll
    for (int nf = 0; nf < 8; nf++)
      a0[nf] = __builtin_amdgcn_mfma_f32_16x16x32_bf16(wfa[nf], bf0, a0[nf], 0, 0, 0);
    bias_act<true>(a0, b0, q);
    layernorm(a0, g0, be0, q);

    f32x4 a1[8];
#pragma unroll
    for (int nf = 0; nf < 8; nf++) a1[nf] = (f32x4){0.f, 0.f, 0.f, 0.f};
    chained_gemm(Wm1, cbb, t, q, a0, a1);
    bias_act<true>(a1, b1, q);
    add_reg(a1, a0);
    layernorm(a1, g1, be1, q);
    store_row(out, mrow, a1, q);

    grp = nxt; c0 = n0; c1 = n1;
  }
}

// cc layer with FUSED gather: bfr = gather(cgA, CSR_cc); GEMM + elu + skip(cgA) -> G
__global__ __launch_bounds__(512, 1) void cc_fused_kernel(
    const ushort* __restrict__ cgA, int ngrp,
    const int* __restrict__ offs, const int* __restrict__ cnt,
    const int* __restrict__ sorted, const float* __restrict__ dout,
    const float* __restrict__ din,
    const ushort* __restrict__ Wsw, const float* __restrict__ bias,
    ushort* __restrict__ outG) {
  __shared__ ushort Wl[16384];
  int tid = threadIdx.x;
  stage_w(Wsw, Wl, tid);
  int lane = tid & 63, wave = tid >> 6;
  int t = lane & 15, q = lane >> 4;
  __syncthreads();
  for (int grp = blockIdx.x; grp < ngrp; grp += gridDim.x) {
    int nd = grp * 128 + wave * 16 + t;
    size_t mrow = (size_t)nd * H;
    bf16x8 bfr[4];
    gather_bfrag(cgA, sorted, offs[nd], cnt[nd], dout, din[nd], q, bfr);
    ushort4 sk[8];
    load_skip_raw(cgA, mrow, q, sk);
    f32x4 a[8];
#pragma unroll
    for (int nf = 0; nf < 8; nf++) a[nf] = (f32x4){0.f, 0.f, 0.f, 0.f};
    gemm128_lds(Wl, bfr, a, t, q);
    bias_act<true>(a, bias, q);
    add_skip_r(a, sk);
    store_row(outG, mrow, a, q);
  }
}

// FUSED gather(G, CSR_ca) -> ca GEMM (elu, +Hb skip) -> m2 (elu, reg-skip, LN)
// -> final (LN) -> AGG. 2 groups/wave share W reads. LDS = 96KB W + 32KB chain.
__global__ __launch_bounds__(512, 1) void fused3_kernel(
    const ushort* __restrict__ G, const ushort* __restrict__ Hbskip, int ngrp,
    const int* __restrict__ offs, const int* __restrict__ cnt,
    const int* __restrict__ sorted, const float* __restrict__ dout,
    const float* __restrict__ din,
    const ushort* __restrict__ Wswca, const float* __restrict__ bca,
    const ushort* __restrict__ Wswm2, const float* __restrict__ bm2,
    const float* __restrict__ gm2, const float* __restrict__ bem2,
    const ushort* __restrict__ Wswf, const float* __restrict__ bf,
    const float* __restrict__ gf, const float* __restrict__ bef,
    ushort* __restrict__ out) {
  __shared__ ushort Wca[16384], Wm2[16384], Wf[16384];
  __shared__ ushort chain[8 * 2048];
  int tid = threadIdx.x;
  stage_w(Wswca, Wca, tid);
  stage_w(Wswm2, Wm2, tid);
  stage_w(Wswf, Wf, tid);
  int lane = tid & 63, wave = tid >> 6;
  int t = lane & 15, q = lane >> 4;
  char* cb0 = (char*)chain + wave * 4096;
  char* cb1 = cb0 + 2048;
  __syncthreads();

  for (int grp = blockIdx.x; grp < ngrp; grp += gridDim.x) {
    int base = grp * 256 + wave * 32;
    int nd0 = base + t, nd1 = base + 16 + t;
    size_t mrow0 = (size_t)nd0 * H;
    size_t mrow1 = (size_t)nd1 * H;

    bf16x8 bfr[2][4];
    gather_bfrag(G, sorted, offs[nd0], cnt[nd0], dout, din[nd0], q, bfr[0]);
    gather_bfrag(G, sorted, offs[nd1], cnt[nd1], dout, din[nd1], q, bfr[1]);
    ushort4 sk[2][8];
    load_skip_raw(Hbskip, mrow0, q, sk[0]);
    load_skip_raw(Hbskip, mrow1, q, sk[1]);

    f32x4 a1[2][8];
#pragma unroll
    for (int g = 0; g < 2; g++)
#pragma unroll
      for (int nf = 0; nf < 8; nf++) a1[g][nf] = (f32x4){0.f, 0.f, 0.f, 0.f};
    gemm128_lds2(Wca, bfr[0], bfr[1], a1[0], a1[1], t, q);
#pragma unroll
    for (int g = 0; g < 2; g++) {
      bias_act<true>(a1[g], bca, q);
      add_skip_r(a1[g], sk[g]);
    }

    f32x4 a2[2][8];
#pragma unroll
    for (int g = 0; g < 2; g++)
#pragma unroll
      for (int nf = 0; nf < 8; nf++) a2[g][nf] = (f32x4){0.f, 0.f, 0.f, 0.f};
    chained_gemm2(Wm2, cb0, cb1, t, q, a1[0], a1[1], a2[0], a2[1]);
#pragma unroll
    for (int g = 0; g < 2; g++) {
      bias_act<true>(a2[g], bm2, q);
      add_reg(a2[g], a1[g]);
      layernorm(a2[g], gm2, bem2, q);
    }

    f32x4 a3[2][8];
#pragma unroll
    for (int g = 0; g < 2; g++)
#pragma unroll
      for (int nf = 0; nf < 8; nf++) a3[g][nf] = (f32x4){0.f, 0.f, 0.f, 0.f};
    chained_gemm2(Wf, cb0, cb1, t, q, a2[0], a2[1], a3[0], a3[1]);
#pragma unroll
    for (int g = 0; g < 2; g++) {
      bias_act<false>(a3[g], bf, q);
      layernorm(a3[g], gf, bef, q);
    }
    store_row(out, mrow0, a3[0], q);
    store_row(out, mrow1, a3[1], q);
  }
}

// ================= VALU GEMM for the cg input MLP (K=32, fp32 in) =================
template<int K, bool ACT, bool LN>
__global__ __launch_bounds__(512) void gemm_fused(
    const float* __restrict__ Av, int ntiles,
    const float* __restrict__ W, const float* __restrict__ bias,
    const float* __restrict__ gamma, const float* __restrict__ beta,
    ushort* __restrict__ out) {
  constexpr int AS = K + 4;
  constexpr int KM = K - 1;
  constexpr int F4R = K / 4;
  __shared__ float Wl[K * H];
  __shared__ float Al[128 * AS];
  int tid = threadIdx.x;

  for (int q = tid; q < K * H / 4; q += 512)
    *(float4*)&Wl[q * 4] = *(const float4*)&W[q * 4];

  int tc = tid & 31, tr = tid >> 5;
  const int rot = (4 * tr) & KM;
  const int c = 4 * tc;
  const float* aBase = Al + (tr * 8) * AS;

  for (int tile = blockIdx.x; tile < ntiles; tile += gridDim.x) {
    int r0 = tile * 128;
    __syncthreads();
    for (int q = tid; q < 128 * F4R; q += 512) {
      int r = q / F4R, cc = (q % F4R) * 4;
      float4 v = *(const float4*)(Av + (size_t)(r0 + r) * K + cc);
      int rr = (4 * (r >> 3)) & KM;
      *(float4*)&Al[r * AS + ((cc + rr) & KM)] = v;
    }
    __syncthreads();

    float4 acc[8];
#pragma unroll
    for (int i = 0; i < 8; i++) acc[i] = make_float4(0.f, 0.f, 0.f, 0.f);

#pragma unroll 2
    for (int k = 0; k < K; k += 4) {
      int kp = (k + rot) & KM;
      float4 av[8];
#pragma unroll
      for (int r8 = 0; r8 < 8; r8++) av[r8] = *(const float4*)(aBase + r8 * AS + kp);
      float4 w0 = *(const float4*)&Wl[(k + 0) * H + c];
      float4 w1 = *(const float4*)&Wl[(k + 1) * H + c];
      float4 w2 = *(const float4*)&Wl[(k + 2) * H + c];
      float4 w3 = *(const float4*)&Wl[(k + 3) * H + c];
#pragma unroll
      for (int r8 = 0; r8 < 8; r8++) {
        float4 a = av[r8];
        fma4(acc[r8], a.x, w0); fma4(acc[r8], a.y, w1);
        fma4(acc[r8], a.z, w2); fma4(acc[r8], a.w, w3);
      }
    }

    float4 bA = *(const float4*)&bias[c];
    float4 gA, beA;
    if constexpr (LN) {
      gA = *(const float4*)&gamma[c];
      beA = *(const float4*)&beta[c];
    }
#pragma unroll
    for (int r8 = 0; r8 < 8; r8++) {
      int r = tr * 8 + r8;
      size_t grow = (size_t)(r0 + r) * H;
      float4 v;
      v.x = acc[r8].x + bA.x; v.y = acc[r8].y + bA.y;
      v.z = acc[r8].z + bA.z; v.w = acc[r8].w + bA.w;
      if constexpr (ACT) {
        v.x = elu(v.x); v.y = elu(v.y); v.z = elu(v.z); v.w = elu(v.w);
      }
      if constexpr (LN) {
        float s = v.x + v.y + v.z + v.w;
        s += __shfl_xor(s, 1); s += __shfl_xor(s, 2);
        s += __shfl_xor(s, 4); s += __shfl_xor(s, 8); s += __shfl_xor(s, 16);
        float mu = s * 0.0078125f;
        float t, d;
        t = v.x - mu; d = t * t;  t = v.y - mu; d += t * t;
        t = v.z - mu; d += t * t; t = v.w - mu; d += t * t;
        d += __shfl_xor(d, 1); d += __shfl_xor(d, 2);
        d += __shfl_xor(d, 4); d += __shfl_xor(d, 8); d += __shfl_xor(d, 16);
        float rs = rsqrtf(d * 0.0078125f + 1e-5f);
        v.x = (v.x - mu) * rs * gA.x + beA.x; v.y = (v.y - mu) * rs * gA.y + beA.y;
        v.z = (v.z - mu) * rs * gA.z + beA.z; v.w = (v.w - mu) * rs * gA.w + beA.w;
      }
      *(ushort4*)&out[grow + c] = make_ushort4(f2bf(v.x), f2bf(v.y), f2bf(v.z), f2bf(v.w));
    }
  }
}

// ================= pooling =================
__global__ __launch_bounds__(128) void pool_sum_kernel(const ushort* __restrict__ h,
                                                       const int* __restrict__ gid,
                                                       float* __restrict__ sums) {
  int f = threadIdx.x;
  int chunk = N_AA / gridDim.x;
  int start = blockIdx.x * chunk, end = start + chunk;
  int g = gid[start];
  float acc = 0.f;
  for (int i = start; i < end; ++i) {
    int gi = gid[i];
    if (gi != g) { atomicAdd(&sums[g * H + f], acc); acc = 0.f; g = gi; }
    acc += bf2f(h[(size_t)i * H + f]);
  }
  atomicAdd(&sums[g * H + f], acc);
}

__global__ void pool_final_kernel(const float* __restrict__ sums, const int* __restrict__ counts,
                                  float* __restrict__ out) {
  int b = blockIdx.x, f = threadIdx.x;
  float c = (float)counts[b];
  out[b * H + f] = sums[b * H + f] / fmaxf(c, 1.f);
  if (f == 0) out[B_GR * H + b] = c;
}

// ================= launch =================
extern "C" void kernel_launch(void* const* d_in, const int* in_sizes, int n_in,
                              void* d_out, int out_size, void* d_ws, size_t ws_size,
                              hipStream_t stream) {
  (void)in_sizes; (void)n_in; (void)out_size; (void)ws_size;
  const float* h_aa0 = (const float*)d_in[0];
  const float* h_cg0 = (const float*)d_in[1];
  const int* src_cc = (const int*)d_in[2];
  const int* dst_cc = (const int*)d_in[3];
  const int* src_ca = (const int*)d_in[4];
  const int* dst_ca = (const int*)d_in[5];
  // d_in[6], d_in[7] (src_ac/dst_ac): dead in the reference — outputs depend only on h_aa
  const int* graph_id = (const int*)d_in[8];
  const float* W_cg0 = (const float*)d_in[9];
  const float* b_cg0 = (const float*)d_in[10];
  const float* g_cg0 = (const float*)d_in[11];
  const float* be_cg0 = (const float*)d_in[12];
  const float* W_aa0 = (const float*)d_in[13];
  const float* b_aa0 = (const float*)d_in[14];
  const float* g_aa0 = (const float*)d_in[15];
  const float* be_aa0 = (const float*)d_in[16];
  const float* W_cc = (const float*)d_in[17];
  const float* b_cc = (const float*)d_in[18];
  const float* W_m1 = (const float*)d_in[19];
  const float* b_m1 = (const float*)d_in[20];
  const float* g_m1 = (const float*)d_in[21];
  const float* be_m1 = (const float*)d_in[22];
  const float* W_ca = (const float*)d_in[23];
  const float* b_ca = (const float*)d_in[24];
  const float* W_m2 = (const float*)d_in[25];
  const float* b_m2 = (const float*)d_in[26];
  const float* g_m2 = (const float*)d_in[27];
  const float* be_m2 = (const float*)d_in[28];
  // d_in[29], d_in[30] (W_ac/b_ac): dead
  const float* W_f = (const float*)d_in[31];
  const float* b_f = (const float*)d_in[32];
  const float* g_f = (const float*)d_in[33];
  const float* be_f = (const float*)d_in[34];

  char* ws = (char*)d_ws;
  size_t off = 0;
  auto alloc = [&](size_t bytes) -> void* {
    void* p = ws + off;
    off = (off + bytes + 255) & ~(size_t)255;
    return p;
  };
  ushort* cgA = (ushort*)alloc((size_t)N_CG * H * 2);
  ushort* G   = (ushort*)alloc((size_t)N_CG * H * 2);
  ushort* Hb  = (ushort*)alloc((size_t)N_AA * H * 2);
  ushort* AGG = (ushort*)alloc((size_t)N_AA * H * 2);
  int* cnt_s_cc = (int*)alloc((size_t)N_CG * 4);  // contiguous 4-array block (one memset, one deg)
  int* cnt_d_cc = (int*)alloc((size_t)N_CG * 4);
  int* cnt_s_ca = (int*)alloc((size_t)N_CG * 4);
  int* cnt_d_ca = (int*)alloc((size_t)N_AA * 4);
  float* dout_cc = (float*)alloc((size_t)N_CG * 4);  // contiguous, same order as counts
  float* din_cc  = (float*)alloc((size_t)N_CG * 4);
  float* dout_ca = (float*)alloc((size_t)N_CG * 4);
  float* din_ca  = (float*)alloc((size_t)N_AA * 4);
  int* offs_cc = (int*)alloc((size_t)N_CG * 4);
  int* cur_cc  = (int*)alloc((size_t)N_CG * 4);
  int* offs_ca = (int*)alloc((size_t)N_AA * 4);
  int* cur_ca  = (int*)alloc((size_t)N_AA * 4);
  int* sorted_cc = (int*)alloc((size_t)E_CC * 4);
  int* sorted_ca = (int*)alloc((size_t)E_CA * 4);
  int* bsum = (int*)alloc(320 * 4);
  float* sums = (float*)alloc((size_t)B_GR * H * 4);
  int* counts = (int*)alloc(256);
  ushort* Wsw_cc = (ushort*)alloc(H * H * 2);
  ushort* Wsw_m1 = (ushort*)alloc(H * H * 2);
  ushort* Wsw_ca = (ushort*)alloc(H * H * 2);
  ushort* Wsw_m2 = (ushort*)alloc(H * H * 2);
  ushort* Wsw_f  = (ushort*)alloc(H * H * 2);
  ushort* Wp_aa  = (ushort*)alloc(H * 32 * 2);

  hipMemsetAsync(cnt_s_cc, 0, (size_t)(3 * N_CG + N_AA) * 4, stream);
  hipMemsetAsync(sums, 0, (size_t)B_GR * H * 4, stream);

  // prep: weights, histograms, graph counts, degrees
  wprep_kernel<<<336, 256, 0, stream>>>(W_cc, W_m1, W_ca, W_m2, W_f,
                                        Wsw_cc, Wsw_m1, Wsw_ca, Wsw_m2, Wsw_f,
                                        W_aa0, Wp_aa);
  hist4_kernel<<<2048, 256, 0, stream>>>(src_cc, dst_cc, src_ca, dst_ca,
                                         cnt_s_cc, cnt_d_cc, cnt_s_ca, cnt_d_ca);
  graph_count_kernel<<<1, 64, 0, stream>>>(graph_id, N_AA, counts);
  deg_all_kernel<<<(3 * N_CG + N_AA) / 256, 256, 0, stream>>>(cnt_s_cc, dout_cc);

  // CSR build (cc + ca merged)
  scan1_kernel<<<320, 256, 0, stream>>>(cnt_d_cc, offs_cc, cnt_d_ca, offs_ca, bsum);
  scan2_kernel<<<2, 256, 0, stream>>>(bsum);
  scan3_kernel<<<(N_CG + N_AA) / 256, 256, 0, stream>>>(offs_cc, cur_cc, offs_ca, cur_ca, bsum);
  place2_kernel<<<2048, 256, 0, stream>>>(src_cc, dst_cc, src_ca, dst_ca,
                                          cur_cc, sorted_cc, cur_ca, sorted_ca);

  // cg input MLP (VALU, fp32 in)
  gemm_fused<32, true, true><<<N_CG / 128, 512, 0, stream>>>(
      h_cg0, N_CG / 128, W_cg0, b_cg0, g_cg0, be_cg0, cgA);

  // aa input MLP + m1 fused -> Hb (round-8 proven: 512 persistent blocks + prefetch)
  fused_aa_kernel<<<512, 512, 0, stream>>>(
      h_aa0, N_AA / 128, Wp_aa, b_aa0, g_aa0, be_aa0,
      Wsw_m1, b_m1, g_m1, be_m1, Hb);

  // cg_to_cg: fused gather + GEMM(+elu) + skip(cgA) -> G
  cc_fused_kernel<<<N_CG / 128, 512, 0, stream>>>(
      cgA, N_CG / 128, offs_cc, cnt_d_cc, sorted_cc, dout_cc, din_cc,
      Wsw_cc, b_cc, G);

  // fused gather(G) + ca + m2 + final -> AGG (256 persistent blocks)
  fused3_kernel<<<256, 512, 0, stream>>>(
      G, Hb, N_AA / 256, offs_ca, cnt_d_ca, sorted_ca, dout_ca, din_ca,
      Wsw_ca, b_ca, Wsw_m2, b_m2, g_m2, be_m2,
      Wsw_f, b_f, g_f, be_f, AGG);

  // mean pool per graph
  pool_sum_kernel<<<1024, 128, 0, stream>>>(AGG, graph_id, sums);
  pool_final_kernel<<<B_GR, 128, 0, stream>>>(sums, counts, (float*)d_out);
}